// Round 8
// baseline (302.719 us; speedup 1.0000x reference)
//
#include <hip/hip_runtime.h>
#include <math.h>

#define IN_C   128
#define OUT_C  64
#define CDIM   512
#define HW     128   // input spatial (half-res)
#define PHW    130   // padded
#define OHW    256   // output spatial
#define NB     8     // batch

typedef __attribute__((ext_vector_type(8))) short short8;
typedef __attribute__((ext_vector_type(4))) float f32x4;

__device__ inline unsigned short f2bf(float f) {
    unsigned int u = __float_as_uint(f);
    unsigned int r = (u + 0x7fffu + ((u >> 16) & 1u)) >> 16;
    return (unsigned short)r;
}

__device__ inline float postact(float v) {
    v = v > 0.f ? v : 0.2f * v;
    v *= 1.4142135623730951f;
    return fminf(fmaxf(v, -256.f), 256.f);
}

__device__ __forceinline__ void gload16(const void* g, void* l) {
    __builtin_amdgcn_global_load_lds(
        (const __attribute__((address_space(1))) unsigned int*)g,
        (__attribute__((address_space(3))) unsigned int*)l, 16, 0, 0);
}

// ================= fused prep: wbprep (blocks 0..1151) + border (1152..1409) + gain (1410..1665)
// wb2 layout (A fragment-linear, REGION-MAJOR):
//   flat = kt*16384 + pr*512 + lane*8 + e,  pr = hh*16 + kc*8 + wM*4 + fi
//   holds Wb[m][ic] for m = (wM*8 + hh*4 + fi)*16 + (lane&15),
//                       ic = (kt&1)*64 + kc*32 + (lane>>4)*8 + e,  tap = kt>>1
__global__ __launch_bounds__(256) void prep_kernel(
    const float* __restrict__ w, unsigned short* __restrict__ wb2,
    unsigned short* __restrict__ xg,
    const float* __restrict__ c, const float* __restrict__ wa,
    const float* __restrict__ ba, float* __restrict__ gain) {
    int blk = blockIdx.x;
    if (blk < 1152) {
        int idx  = blk * 256 + threadIdx.x;          // 18*16384 total
        int e    = idx & 7;
        int lane = (idx >> 3) & 63;
        int pr   = (idx >> 9) & 31;
        int kt   = idx >> 14;                        // 0..17
        int hh = pr >> 4, kcb = (pr >> 3) & 1, wM = (pr >> 2) & 1, fi = pr & 3;
        int m   = (wM * 8 + hh * 4 + fi) * 16 + (lane & 15);
        int ic  = (kt & 1) * 64 + kcb * 32 + (lane >> 4) * 8 + e;
        int tap = kt >> 1;
        int ky = tap / 3, kx = tap % 3;
        int oc = m >> 2, ph = m & 3;
        int py = ph >> 1, px = ph & 1;
        int sy = 2 * ky + (py == 0 ? 1 : 0);
        int sx = 2 * kx + (px == 0 ? 1 : 0);
        const float k1[4] = {0.25f, 0.75f, 0.75f, 0.25f};
        float sum = 0.f;
        #pragma unroll
        for (int by = 0; by < 3; ++by) {
            int ay = sy - by;
            if (ay < 0 || ay > 3) continue;
            #pragma unroll
            for (int bx = 0; bx < 3; ++bx) {
                int ax = sx - bx;
                if (ax < 0 || ax > 3) continue;
                sum += w[((oc * IN_C + ic) * 3 + (2 - by)) * 3 + (2 - bx)] * k1[ay] * k1[ax];
            }
        }
        wb2[idx] = f2bf(sum * 0.029462782549439483f);   // 1/sqrt(1152)
    } else if (blk < 1410) {
        int id = (blk - 1152) * 256 + threadIdx.x;   // 8*516*16 = 66048 exact
        int cc = id & 15;
        int t  = id >> 4;
        int p  = t % 516;
        int n  = t / 516;
        int Y, X;
        if (p < 130)      { Y = 0;   X = p; }
        else if (p < 260) { Y = 129; X = p - 130; }
        else              { int q = p - 260; Y = 1 + (q >> 1); X = (q & 1) * 129; }
        uint4 z = make_uint4(0, 0, 0, 0);
        *reinterpret_cast<uint4*>(xg + (((size_t)(n * PHW) + Y) * PHW + X) * 128 + cc * 8) = z;
    } else {
        int wave = (blk - 1410) * 4 + (threadIdx.x >> 6);   // 0..1023
        int lane = threadIdx.x & 63;
        int n  = wave >> 7;
        int ic = wave & 127;
        const float* cp = c + n * CDIM;
        const float* wp = wa + ic * CDIM;
        float s = 0.f;
        #pragma unroll
        for (int k = 0; k < CDIM / 64; ++k) s += cp[lane + 64 * k] * wp[lane + 64 * k];
        #pragma unroll
        for (int off = 32; off > 0; off >>= 1) s += __shfl_down(s, off);
        if (lane == 0) {
            float y = s * 0.04419417382415922f + ba[ic];
            gain[n * IN_C + ic] = 1.0f + tanhf(y);
        }
    }
}

// ---------------- xprep: padded 130x130 NHWC bf16, 16B-chunk order XOR-swizzled by (X&7)
__global__ __launch_bounds__(256) void xprep_kernel(const float* __restrict__ x,
                                                    const float* __restrict__ gain,
                                                    unsigned short* __restrict__ xg) {
    int n = blockIdx.x >> 7;
    int y = blockIdx.x & 127;
    __shared__ unsigned short lds[128][130];
    int tid = threadIdx.x;
    for (int i = tid; i < 128 * 128; i += 256) {
        int ic = i >> 7, pix = i & 127;
        float v = x[(((n * IN_C + ic) * HW) + y) * HW + pix] * gain[n * IN_C + ic];
        lds[pix][ic] = f2bf(v);
    }
    __syncthreads();
    unsigned int* dst = (unsigned int*)(xg + (((size_t)(n * PHW) + y + 1) * PHW + 1) * 128);
    for (int i = tid; i < 8192; i += 256) {
        int pix = i >> 6, d = i & 63;
        int j = d >> 2, ww = d & 3;
        int js = j ^ ((pix + 1) & 7);          // swizzle key = padded X & 7
        dst[pix * 64 + js * 4 + ww] = *reinterpret_cast<const unsigned int*>(&lds[pix][d * 2]);
    }
}

// ---------------- main conv: M=256 x N=256px x K=1152.
// B halo (18x18x128 bf16 = 83KB) LDS-resident (read-only after one barrier).
// A: software-pipelined global->register double-buffer (half-K-step granularity).
// 16 waves/block (1024 thr) -> 4 waves/SIMD at 1 block/CU. No K-loop barriers.
#define MM(ACC, AF, BF) ACC = __builtin_amdgcn_mfma_f32_16x16x32_bf16(AF, BF, ACC, 0, 0, 0)

__global__ __launch_bounds__(1024, 4) void conv_mfma7(
    const unsigned short* __restrict__ xg,
    const unsigned short* __restrict__ wb2,
    const float* __restrict__ bias,
    float* __restrict__ out) {
    __shared__ __align__(16) char haloB[82944];   // 18 rows x 18 px x 256B

    const int bid = blockIdx.x;                 // 512 blocks; bijective XCD swizzle (512%8==0)
    const int wg  = ((bid & 7) << 6) + (bid >> 3);
    const int n     = wg >> 6;
    const int patch = wg & 63;
    const int Y0 = (patch >> 3) * 16;
    const int X0 = (patch & 7) * 16;            // mult of 8 -> swizzle key block-independent
    const int tid  = threadIdx.x;
    const int lane = tid & 63;
    const int wid  = tid >> 6;                  // 0..15
    const int wM = wid & 1;                     // SIMD-cohabiting waves {w,w+4,w+8,w+12} share wM
    const int wN = wid >> 1;                    // 0..7 -> rows [2wN, 2wN+1]
    const int l16 = lane & 15;
    const int lhi = lane >> 4;
    const int wN2 = wN * 2;

    const char* xgb = (const char*)xg + (size_t)n * PHW * PHW * 256;

    // ---- stage B halo once: 18 rows x 18 px x 256B = 5184 chunks of 16B, linear LDS
    #pragma unroll 1
    for (int i = 0; i < 6; ++i) {
        int cc = i * 1024 + tid;
        if (cc < 5184) {                        // 5184 % 64 == 0 -> wave-uniform cutoff
            int r = cc / 288;
            int t2 = cc - r * 288;
            gload16(xgb + ((size_t)(Y0 + r) * PHW + X0) * 256 + t2 * 16,
                    haloB + (i * 1024 + wid * 64) * 16);
        }
    }

    // per-lane A base: frag (f) of half-step (t,kc) lives at
    //   abase + t*32768 + kc*8192 + ((f>>2)*16 + (f&3))*1024
    const char* abase = (const char*)wb2 + (wM << 12) + (lane << 4);

    f32x4 acc[8][2];
    #pragma unroll
    for (int f = 0; f < 8; ++f)
        #pragma unroll
        for (int b = 0; b < 2; ++b) acc[f][b] = (f32x4)0.f;

    __syncthreads();   // halo resident for all waves (drains vmcnt before barrier)

    short8 Aa[8], Ab[8], Bf[2];

    // prime: A(t=0, kc=0)
    #pragma unroll
    for (int f = 0; f < 8; ++f)
        Aa[f] = *reinterpret_cast<const short8*>(abase + ((((f >> 2) << 4) + (f & 3)) << 10));

    #pragma unroll 1
    for (int t = 0; t < 18; ++t) {
        const int tap = t >> 1;
        const int h   = t & 1;
        const int ky  = tap / 3;
        const int kx  = tap - ky * 3;
        const int C   = l16 + kx;
        const int bswz = (C & 7) << 4;
        const int rowb = (wN2 + ky) * 18 + C;
        const char* ak = abase + t * 32768;

        // ===== half kc=0: prefetch A(t,1); read B(kc=0); 16 MFMA on Aa
        #pragma unroll
        for (int f = 0; f < 8; ++f)
            Ab[f] = *reinterpret_cast<const short8*>(ak + 8192 + ((((f >> 2) << 4) + (f & 3)) << 10));
        #pragma unroll
        for (int b = 0; b < 2; ++b)
            Bf[b] = *reinterpret_cast<const short8*>(
                haloB + ((rowb + b * 18) << 8) + (((h << 7) + (lhi << 4)) ^ bswz));
        __builtin_amdgcn_sched_barrier(0);   // keep prefetch+reads above the cluster
        __builtin_amdgcn_s_setprio(1);
        #pragma unroll
        for (int f = 0; f < 8; ++f)
            #pragma unroll
            for (int b = 0; b < 2; ++b) MM(acc[f][b], Aa[f], Bf[b]);
        __builtin_amdgcn_s_setprio(0);

        // ===== half kc=1: prefetch A(t+1,0); read B(kc=1); 16 MFMA on Ab
        if (t + 1 < 18) {
            #pragma unroll
            for (int f = 0; f < 8; ++f)
                Aa[f] = *reinterpret_cast<const short8*>(ak + 32768 + ((((f >> 2) << 4) + (f & 3)) << 10));
        }
        #pragma unroll
        for (int b = 0; b < 2; ++b)
            Bf[b] = *reinterpret_cast<const short8*>(
                haloB + ((rowb + b * 18) << 8) + (((h << 7) + 64 + (lhi << 4)) ^ bswz));
        __builtin_amdgcn_sched_barrier(0);
        __builtin_amdgcn_s_setprio(1);
        #pragma unroll
        for (int f = 0; f < 8; ++f)
            #pragma unroll
            for (int b = 0; b < 2; ++b) MM(acc[f][b], Ab[f], Bf[b]);
        __builtin_amdgcn_s_setprio(0);
    }

    // ---- epilogue: M = wM*128 + f*16 + lhi*4 + r ; oc = M>>2, phase = M&3 = r
    #pragma unroll
    for (int f = 0; f < 8; ++f) {
        const int oc = wM * 32 + f * 4 + lhi;
        const float bi = bias[oc];
        #pragma unroll
        for (int b = 0; b < 2; ++b) {
            const int ypix = Y0 + wN2 + b;
            const int xpix = X0 + l16;
            float* o0 = out + (((size_t)(n * OUT_C + oc) * OHW) + 2 * ypix) * OHW + 2 * xpix;
            float2 v0 = make_float2(postact(acc[f][b][0] + bi), postact(acc[f][b][1] + bi));
            float2 v1 = make_float2(postact(acc[f][b][2] + bi), postact(acc[f][b][3] + bi));
            *reinterpret_cast<float2*>(o0) = v0;
            *reinterpret_cast<float2*>(o0 + OHW) = v1;
        }
    }
}

// ================= fallback f32 path (round-1, verified) =================
__global__ void gain_kernel(const float* __restrict__ c,
                            const float* __restrict__ w_affine,
                            const float* __restrict__ b_affine,
                            float* __restrict__ gain) {
    int wave = (blockIdx.x * blockDim.x + threadIdx.x) >> 6;
    int lane = threadIdx.x & 63;
    if (wave >= NB * IN_C) return;
    int n  = wave >> 7;
    int ic = wave & 127;
    const float* cp = c + n * CDIM;
    const float* wp = w_affine + ic * CDIM;
    float s = 0.f;
    #pragma unroll
    for (int k = 0; k < CDIM / 64; ++k) s += cp[lane + 64 * k] * wp[lane + 64 * k];
    #pragma unroll
    for (int off = 32; off > 0; off >>= 1) s += __shfl_down(s, off);
    if (lane == 0) {
        float y = s * 0.04419417382415922f + b_affine[ic];
        gain[n * IN_C + ic] = 1.0f + tanhf(y);
    }
}

__global__ void wprep_kernel(const float* __restrict__ w, float* __restrict__ wp) {
    int idx = blockIdx.x * blockDim.x + threadIdx.x;
    if (idx >= IN_C * 9 * 4 * OUT_C) return;
    int oc = idx & 63;
    int t  = idx >> 6;
    int ph = t & 3;  t >>= 2;
    int kx = t % 3;  t /= 3;
    int ky = t % 3;  t /= 3;
    int ic = t;
    int py = ph >> 1, px = ph & 1;
    int sy = 2 * ky + (py == 0 ? 1 : 0);
    int sx = 2 * kx + (px == 0 ? 1 : 0);
    const float k1[4] = {0.25f, 0.75f, 0.75f, 0.25f};
    float sum = 0.f;
    #pragma unroll
    for (int by = 0; by < 3; ++by) {
        int ay = sy - by;
        if (ay < 0 || ay > 3) continue;
        #pragma unroll
        for (int bx = 0; bx < 3; ++bx) {
            int ax = sx - bx;
            if (ax < 0 || ax > 3) continue;
            sum += w[((oc * IN_C + ic) * 3 + (2 - by)) * 3 + (2 - bx)] * k1[ay] * k1[ax];
        }
    }
    wp[idx] = sum * 0.029462782549439483f;
}

__global__ __launch_bounds__(256) void conv_main(
    const float* __restrict__ x, const float* __restrict__ gain,
    const float* __restrict__ wp, const float* __restrict__ bias,
    float* __restrict__ out) {
    const int n    = blockIdx.z >> 3;
    const int occ  = (blockIdx.z & 7) * 8;
    const int tx0  = blockIdx.x * 16;
    const int ty0  = blockIdx.y * 16;
    const int tid  = threadIdx.x;
    const int lx   = tid & 15;
    const int ly   = tid >> 4;
    __shared__ float xsf[8][18][18];
    float acc[4][8];
    #pragma unroll
    for (int p = 0; p < 4; ++p)
        #pragma unroll
        for (int o = 0; o < 8; ++o) acc[p][o] = 0.f;
    for (int ic0 = 0; ic0 < IN_C; ic0 += 8) {
        __syncthreads();
        for (int i = tid; i < 8 * 324; i += 256) {
            int icb = i / 324;
            int rem = i - icb * 324;
            int yy  = rem / 18;
            int xx  = rem - yy * 18;
            int gy  = ty0 + yy - 1;
            int gx  = tx0 + xx - 1;
            int ic  = ic0 + icb;
            float v = 0.f;
            if (gy >= 0 && gy < HW && gx >= 0 && gx < HW)
                v = x[((n * IN_C + ic) * HW + gy) * HW + gx] * gain[n * IN_C + ic];
            xsf[icb][yy][xx] = v;
        }
        __syncthreads();
        for (int icb = 0; icb < 8; ++icb) {
            const int ic = ic0 + icb;
            const float* wpp = wp + ic * (9 * 4 * OUT_C) + occ;
            #pragma unroll
            for (int ky = 0; ky < 3; ++ky)
                #pragma unroll
                for (int kx = 0; kx < 3; ++kx) {
                    float tv = xsf[icb][ly + ky][lx + kx];
                    const float* w9 = wpp + (ky * 3 + kx) * (4 * OUT_C);
                    #pragma unroll
                    for (int p = 0; p < 4; ++p)
                        #pragma unroll
                        for (int o = 0; o < 8; ++o)
                            acc[p][o] = fmaf(tv, w9[p * OUT_C + o], acc[p][o]);
                }
        }
    }
    const int ybase = 2 * (ty0 + ly);
    const int xbase = 2 * (tx0 + lx);
    #pragma unroll
    for (int o = 0; o < 8; ++o) {
        float b = bias[occ + o];
        #pragma unroll
        for (int py = 0; py < 2; ++py) {
            float2 v;
            v.x = postact(acc[py * 2 + 0][o] + b);
            v.y = postact(acc[py * 2 + 1][o] + b);
            *reinterpret_cast<float2*>(
                &out[((size_t)(n * OUT_C + occ + o) * OHW + (ybase + py)) * OHW + xbase]) = v;
        }
    }
}

extern "C" void kernel_launch(void* const* d_in, const int* in_sizes, int n_in,
                              void* d_out, int out_size, void* d_ws, size_t ws_size,
                              hipStream_t stream) {
    const float* x        = (const float*)d_in[0];
    const float* c        = (const float*)d_in[1];
    const float* weight   = (const float*)d_in[2];
    const float* bias     = (const float*)d_in[3];
    const float* w_affine = (const float*)d_in[4];
    const float* b_affine = (const float*)d_in[5];
    float* out = (float*)d_out;

    float* gain = (float*)d_ws;   // 4 KB @ 0

    const size_t NEED = 1048576 + (size_t)NB * PHW * PHW * IN_C * 2;  // ~35.7 MB
    if (ws_size >= NEED) {
        unsigned short* wb2 = (unsigned short*)((char*)d_ws + 8192);      // 589824 B
        unsigned short* xg  = (unsigned short*)((char*)d_ws + 1048576);   // 34.6 MB padded+swizzled NHWC
        prep_kernel<<<dim3(1666), dim3(256), 0, stream>>>(weight, wb2, xg, c, w_affine, b_affine, gain);
        xprep_kernel<<<dim3(NB * HW), dim3(256), 0, stream>>>(x, gain, xg);
        conv_mfma7<<<dim3(512), dim3(1024), 0, stream>>>(xg, wb2, bias, out);
    } else {
        float* wp = (float*)((char*)d_ws + 8192);
        gain_kernel<<<dim3((NB * IN_C * 64) / 256), dim3(256), 0, stream>>>(c, w_affine, b_affine, gain);
        wprep_kernel<<<dim3((IN_C * 9 * 4 * OUT_C + 255) / 256), dim3(256), 0, stream>>>(weight, wp);
        conv_main<<<dim3(HW / 16, HW / 16, NB * 8), dim3(256), 0, stream>>>(x, gain, wp, bias, out);
    }
}

// Round 9
// 112.121 us; speedup vs baseline: 2.6999x; 2.6999x over previous
//
#include <hip/hip_runtime.h>
#include <math.h>

#define IN_C   128
#define OUT_C  64
#define CDIM   512
#define HW     128   // input spatial (half-res)
#define PHW    130   // padded
#define OHW    256   // output spatial
#define NB     8     // batch

typedef __attribute__((ext_vector_type(8))) short short8;
typedef __attribute__((ext_vector_type(4))) float f32x4;

__device__ inline unsigned short f2bf(float f) {
    unsigned int u = __float_as_uint(f);
    unsigned int r = (u + 0x7fffu + ((u >> 16) & 1u)) >> 16;
    return (unsigned short)r;
}

__device__ inline float postact(float v) {
    v = v > 0.f ? v : 0.2f * v;
    v *= 1.4142135623730951f;
    return fminf(fmaxf(v, -256.f), 256.f);
}

__device__ __forceinline__ void gload16(const void* g, void* l) {
    __builtin_amdgcn_global_load_lds(
        (const __attribute__((address_space(1))) unsigned int*)g,
        (__attribute__((address_space(3))) unsigned int*)l, 16, 0, 0);
}

// ================= fused prep: wbprep (blocks 0..1151) + border (1152..1409) + gain (1410..1665)
// wb2 layout (A fragment-linear, REGION-MAJOR):
//   flat = kt*16384 + pr*512 + lane*8 + e,  pr = hh*16 + kc*8 + wM*4 + fi
//   holds Wb[m][ic] for m = (wM*8 + hh*4 + fi)*16 + (lane&15),
//                       ic = (kt&1)*64 + kc*32 + (lane>>4)*8 + e,  tap = kt>>1
__global__ __launch_bounds__(256) void prep_kernel(
    const float* __restrict__ w, unsigned short* __restrict__ wb2,
    unsigned short* __restrict__ xg,
    const float* __restrict__ c, const float* __restrict__ wa,
    const float* __restrict__ ba, float* __restrict__ gain) {
    int blk = blockIdx.x;
    if (blk < 1152) {
        int idx  = blk * 256 + threadIdx.x;          // 18*16384 total
        int e    = idx & 7;
        int lane = (idx >> 3) & 63;
        int pr   = (idx >> 9) & 31;
        int kt   = idx >> 14;                        // 0..17
        int hh = pr >> 4, kcb = (pr >> 3) & 1, wM = (pr >> 2) & 1, fi = pr & 3;
        int m   = (wM * 8 + hh * 4 + fi) * 16 + (lane & 15);
        int ic  = (kt & 1) * 64 + kcb * 32 + (lane >> 4) * 8 + e;
        int tap = kt >> 1;
        int ky = tap / 3, kx = tap % 3;
        int oc = m >> 2, ph = m & 3;
        int py = ph >> 1, px = ph & 1;
        int sy = 2 * ky + (py == 0 ? 1 : 0);
        int sx = 2 * kx + (px == 0 ? 1 : 0);
        const float k1[4] = {0.25f, 0.75f, 0.75f, 0.25f};
        float sum = 0.f;
        #pragma unroll
        for (int by = 0; by < 3; ++by) {
            int ay = sy - by;
            if (ay < 0 || ay > 3) continue;
            #pragma unroll
            for (int bx = 0; bx < 3; ++bx) {
                int ax = sx - bx;
                if (ax < 0 || ax > 3) continue;
                sum += w[((oc * IN_C + ic) * 3 + (2 - by)) * 3 + (2 - bx)] * k1[ay] * k1[ax];
            }
        }
        wb2[idx] = f2bf(sum * 0.029462782549439483f);   // 1/sqrt(1152)
    } else if (blk < 1410) {
        int id = (blk - 1152) * 256 + threadIdx.x;   // 8*516*16 = 66048 exact
        int cc = id & 15;
        int t  = id >> 4;
        int p  = t % 516;
        int n  = t / 516;
        int Y, X;
        if (p < 130)      { Y = 0;   X = p; }
        else if (p < 260) { Y = 129; X = p - 130; }
        else              { int q = p - 260; Y = 1 + (q >> 1); X = (q & 1) * 129; }
        uint4 z = make_uint4(0, 0, 0, 0);
        *reinterpret_cast<uint4*>(xg + (((size_t)(n * PHW) + Y) * PHW + X) * 128 + cc * 8) = z;
    } else {
        int wave = (blk - 1410) * 4 + (threadIdx.x >> 6);   // 0..1023
        int lane = threadIdx.x & 63;
        int n  = wave >> 7;
        int ic = wave & 127;
        const float* cp = c + n * CDIM;
        const float* wp = wa + ic * CDIM;
        float s = 0.f;
        #pragma unroll
        for (int k = 0; k < CDIM / 64; ++k) s += cp[lane + 64 * k] * wp[lane + 64 * k];
        #pragma unroll
        for (int off = 32; off > 0; off >>= 1) s += __shfl_down(s, off);
        if (lane == 0) {
            float y = s * 0.04419417382415922f + ba[ic];
            gain[n * IN_C + ic] = 1.0f + tanhf(y);
        }
    }
}

// ---------------- xprep: padded 130x130 NHWC bf16, 16B-chunk order XOR-swizzled by (X&7)
__global__ __launch_bounds__(256) void xprep_kernel(const float* __restrict__ x,
                                                    const float* __restrict__ gain,
                                                    unsigned short* __restrict__ xg) {
    int n = blockIdx.x >> 7;
    int y = blockIdx.x & 127;
    __shared__ unsigned short lds[128][130];
    int tid = threadIdx.x;
    for (int i = tid; i < 128 * 128; i += 256) {
        int ic = i >> 7, pix = i & 127;
        float v = x[(((n * IN_C + ic) * HW) + y) * HW + pix] * gain[n * IN_C + ic];
        lds[pix][ic] = f2bf(v);
    }
    __syncthreads();
    unsigned int* dst = (unsigned int*)(xg + (((size_t)(n * PHW) + y + 1) * PHW + 1) * 128);
    for (int i = tid; i < 8192; i += 256) {
        int pix = i >> 6, d = i & 63;
        int j = d >> 2, ww = d & 3;
        int js = j ^ ((pix + 1) & 7);          // swizzle key = padded X & 7
        dst[pix * 64 + js * 4 + ww] = *reinterpret_cast<const unsigned int*>(&lds[pix][d * 2]);
    }
}

// ---------------- main conv: M=256 x N=256px x K=1152.
// B halo (18x18x128 bf16 = 83KB) LDS-resident. A AND B register-double-buffered one
// half-step ahead; 36 half-steps fully unrolled (all addressing folds to constants).
// No K-loop barriers; compiler-counted vmcnt/lgkmcnt; 2 waves/SIMD by design.
#define MM(ACC, AF, BF) ACC = __builtin_amdgcn_mfma_f32_16x16x32_bf16(AF, BF, ACC, 0, 0, 0)

__global__ __launch_bounds__(512, 2) void conv_mfma8(
    const unsigned short* __restrict__ xg,
    const unsigned short* __restrict__ wb2,
    const float* __restrict__ bias,
    float* __restrict__ out) {
    __shared__ __align__(16) char haloB[82944];   // 18 rows x 18 px x 256B

    const int bid = blockIdx.x;                 // 512 blocks; bijective XCD swizzle (512%8==0)
    const int wg  = ((bid & 7) << 6) + (bid >> 3);
    const int n     = wg >> 6;
    const int patch = wg & 63;
    const int Y0 = (patch >> 3) * 16;
    const int X0 = (patch & 7) * 16;            // mult of 8 -> swizzle key block-independent
    const int tid  = threadIdx.x;
    const int lane = tid & 63;
    const int wid  = tid >> 6;
    const int wM = wid & 1;                     // SIMD-cohabiting waves (wid, wid+4) share wM
    const int wN = wid >> 1;                    // 0..3
    const int l16 = lane & 15;
    const int lhi = lane >> 4;
    const int pbase = wN * 4;

    const char* xgb = (const char*)xg + (size_t)n * PHW * PHW * 256;

    // ---- stage B halo once: 18 rows x 18 px x 256B = 5184 chunks of 16B, linear LDS
    #pragma unroll 1
    for (int i = 0; i < 11; ++i) {
        int cc = i * 512 + tid;
        if (cc < 5184) {
            int r = cc / 288;
            int t2 = cc - r * 288;
            gload16(xgb + ((size_t)(Y0 + r) * PHW + X0) * 256 + t2 * 16,
                    haloB + (i * 512 + wid * 64) * 16);
        }
    }

    // per-lane A base: frag f of half-step s lives at
    //   abase + (s>>1)*32768 + (s&1)*8192 + ((f>>2)*16 + (f&3))*1024
    const char* abase = (const char*)wb2 + (wM << 12) + (lane << 4);

    f32x4 acc[8][4];
    #pragma unroll
    for (int f = 0; f < 8; ++f)
        #pragma unroll
        for (int b = 0; b < 4; ++b) acc[f][b] = (f32x4)0.f;

    __syncthreads();   // halo resident for all waves (drains vmcnt before barrier)

    short8 Aa[8], Ab[8], Ba[4], Bb[4];

    auto loadA = [&](short8 (&A)[8], int s) {
        const char* ak = abase + (s >> 1) * 32768 + (s & 1) * 8192;
        #pragma unroll
        for (int f = 0; f < 8; ++f)
            A[f] = *reinterpret_cast<const short8*>(ak + ((((f >> 2) << 4) + (f & 3)) << 10));
    };
    auto loadB = [&](short8 (&B)[4], int s) {
        const int tap = s >> 2;
        const int h   = (s >> 1) & 1;
        const int kc  = s & 1;
        const int ky  = tap / 3;
        const int kx  = tap - ky * 3;
        const int C   = l16 + kx;
        const int off = ((h << 7) + (kc << 6) + (lhi << 4)) ^ ((C & 7) << 4);
        #pragma unroll
        for (int b = 0; b < 4; ++b)
            B[b] = *reinterpret_cast<const short8*>(
                haloB + (((pbase + ky + b) * 18 + C) << 8) + off);
    };
    auto cluster = [&](short8 (&A)[8], short8 (&B)[4]) {
        __builtin_amdgcn_s_setprio(1);
        #pragma unroll
        for (int f = 0; f < 8; ++f)
            #pragma unroll
            for (int b = 0; b < 4; ++b) MM(acc[f][b], A[f], B[b]);
        __builtin_amdgcn_s_setprio(0);
    };

    // prime half-step 0
    loadA(Aa, 0); loadB(Ba, 0);

    #pragma unroll
    for (int s = 0; s < 36; ++s) {
        if (s + 1 < 36) {
            if (s & 1) { loadA(Aa, s + 1); loadB(Ba, s + 1); }
            else       { loadA(Ab, s + 1); loadB(Bb, s + 1); }
        }
        __builtin_amdgcn_sched_barrier(0);   // prefetch stays above the cluster
        if (s & 1) cluster(Ab, Bb);
        else       cluster(Aa, Ba);
    }

    // ---- epilogue: M = wM*128 + f*16 + lhi*4 + r ; oc = M>>2, phase = M&3 = r
    #pragma unroll
    for (int f = 0; f < 8; ++f) {
        const int oc = wM * 32 + f * 4 + lhi;
        const float bi = bias[oc];
        #pragma unroll
        for (int b = 0; b < 4; ++b) {
            const int ypix = Y0 + pbase + b;
            const int xpix = X0 + l16;
            float* o0 = out + (((size_t)(n * OUT_C + oc) * OHW) + 2 * ypix) * OHW + 2 * xpix;
            float2 v0 = make_float2(postact(acc[f][b][0] + bi), postact(acc[f][b][1] + bi));
            float2 v1 = make_float2(postact(acc[f][b][2] + bi), postact(acc[f][b][3] + bi));
            *reinterpret_cast<float2*>(o0) = v0;
            *reinterpret_cast<float2*>(o0 + OHW) = v1;
        }
    }
}

// ================= fallback f32 path (round-1, verified) =================
__global__ void gain_kernel(const float* __restrict__ c,
                            const float* __restrict__ w_affine,
                            const float* __restrict__ b_affine,
                            float* __restrict__ gain) {
    int wave = (blockIdx.x * blockDim.x + threadIdx.x) >> 6;
    int lane = threadIdx.x & 63;
    if (wave >= NB * IN_C) return;
    int n  = wave >> 7;
    int ic = wave & 127;
    const float* cp = c + n * CDIM;
    const float* wp = w_affine + ic * CDIM;
    float s = 0.f;
    #pragma unroll
    for (int k = 0; k < CDIM / 64; ++k) s += cp[lane + 64 * k] * wp[lane + 64 * k];
    #pragma unroll
    for (int off = 32; off > 0; off >>= 1) s += __shfl_down(s, off);
    if (lane == 0) {
        float y = s * 0.04419417382415922f + b_affine[ic];
        gain[n * IN_C + ic] = 1.0f + tanhf(y);
    }
}

__global__ void wprep_kernel(const float* __restrict__ w, float* __restrict__ wp) {
    int idx = blockIdx.x * blockDim.x + threadIdx.x;
    if (idx >= IN_C * 9 * 4 * OUT_C) return;
    int oc = idx & 63;
    int t  = idx >> 6;
    int ph = t & 3;  t >>= 2;
    int kx = t % 3;  t /= 3;
    int ky = t % 3;  t /= 3;
    int ic = t;
    int py = ph >> 1, px = ph & 1;
    int sy = 2 * ky + (py == 0 ? 1 : 0);
    int sx = 2 * kx + (px == 0 ? 1 : 0);
    const float k1[4] = {0.25f, 0.75f, 0.75f, 0.25f};
    float sum = 0.f;
    #pragma unroll
    for (int by = 0; by < 3; ++by) {
        int ay = sy - by;
        if (ay < 0 || ay > 3) continue;
        #pragma unroll
        for (int bx = 0; bx < 3; ++bx) {
            int ax = sx - bx;
            if (ax < 0 || ax > 3) continue;
            sum += w[((oc * IN_C + ic) * 3 + (2 - by)) * 3 + (2 - bx)] * k1[ay] * k1[ax];
        }
    }
    wp[idx] = sum * 0.029462782549439483f;
}

__global__ __launch_bounds__(256) void conv_main(
    const float* __restrict__ x, const float* __restrict__ gain,
    const float* __restrict__ wp, const float* __restrict__ bias,
    float* __restrict__ out) {
    const int n    = blockIdx.z >> 3;
    const int occ  = (blockIdx.z & 7) * 8;
    const int tx0  = blockIdx.x * 16;
    const int ty0  = blockIdx.y * 16;
    const int tid  = threadIdx.x;
    const int lx   = tid & 15;
    const int ly   = tid >> 4;
    __shared__ float xsf[8][18][18];
    float acc[4][8];
    #pragma unroll
    for (int p = 0; p < 4; ++p)
        #pragma unroll
        for (int o = 0; o < 8; ++o) acc[p][o] = 0.f;
    for (int ic0 = 0; ic0 < IN_C; ic0 += 8) {
        __syncthreads();
        for (int i = tid; i < 8 * 324; i += 256) {
            int icb = i / 324;
            int rem = i - icb * 324;
            int yy  = rem / 18;
            int xx  = rem - yy * 18;
            int gy  = ty0 + yy - 1;
            int gx  = tx0 + xx - 1;
            int ic  = ic0 + icb;
            float v = 0.f;
            if (gy >= 0 && gy < HW && gx >= 0 && gx < HW)
                v = x[((n * IN_C + ic) * HW + gy) * HW + gx] * gain[n * IN_C + ic];
            xsf[icb][yy][xx] = v;
        }
        __syncthreads();
        for (int icb = 0; icb < 8; ++icb) {
            const int ic = ic0 + icb;
            const float* wpp = wp + ic * (9 * 4 * OUT_C) + occ;
            #pragma unroll
            for (int ky = 0; ky < 3; ++ky)
                #pragma unroll
                for (int kx = 0; kx < 3; ++kx) {
                    float tv = xsf[icb][ly + ky][lx + kx];
                    const float* w9 = wpp + (ky * 3 + kx) * (4 * OUT_C);
                    #pragma unroll
                    for (int p = 0; p < 4; ++p)
                        #pragma unroll
                        for (int o = 0; o < 8; ++o)
                            acc[p][o] = fmaf(tv, w9[p * OUT_C + o], acc[p][o]);
                }
        }
    }
    const int ybase = 2 * (ty0 + ly);
    const int xbase = 2 * (tx0 + lx);
    #pragma unroll
    for (int o = 0; o < 8; ++o) {
        float b = bias[occ + o];
        #pragma unroll
        for (int py = 0; py < 2; ++py) {
            float2 v;
            v.x = postact(acc[py * 2 + 0][o] + b);
            v.y = postact(acc[py * 2 + 1][o] + b);
            *reinterpret_cast<float2*>(
                &out[((size_t)(n * OUT_C + occ + o) * OHW + (ybase + py)) * OHW + xbase]) = v;
        }
    }
}

extern "C" void kernel_launch(void* const* d_in, const int* in_sizes, int n_in,
                              void* d_out, int out_size, void* d_ws, size_t ws_size,
                              hipStream_t stream) {
    const float* x        = (const float*)d_in[0];
    const float* c        = (const float*)d_in[1];
    const float* weight   = (const float*)d_in[2];
    const float* bias     = (const float*)d_in[3];
    const float* w_affine = (const float*)d_in[4];
    const float* b_affine = (const float*)d_in[5];
    float* out = (float*)d_out;

    float* gain = (float*)d_ws;   // 4 KB @ 0

    const size_t NEED = 1048576 + (size_t)NB * PHW * PHW * IN_C * 2;  // ~35.7 MB
    if (ws_size >= NEED) {
        unsigned short* wb2 = (unsigned short*)((char*)d_ws + 8192);      // 589824 B
        unsigned short* xg  = (unsigned short*)((char*)d_ws + 1048576);   // 34.6 MB padded+swizzled NHWC
        prep_kernel<<<dim3(1666), dim3(256), 0, stream>>>(weight, wb2, xg, c, w_affine, b_affine, gain);
        xprep_kernel<<<dim3(NB * HW), dim3(256), 0, stream>>>(x, gain, xg);
        conv_mfma8<<<dim3(512), dim3(512), 0, stream>>>(xg, wb2, bias, out);
    } else {
        float* wp = (float*)((char*)d_ws + 8192);
        gain_kernel<<<dim3((NB * IN_C * 64) / 256), dim3(256), 0, stream>>>(c, w_affine, b_affine, gain);
        wprep_kernel<<<dim3((IN_C * 9 * 4 * OUT_C + 255) / 256), dim3(256), 0, stream>>>(weight, wp);
        conv_main<<<dim3(HW / 16, HW / 16, NB * 8), dim3(256), 0, stream>>>(x, gain, wp, bias, out);
    }
}

// Round 10
// 103.735 us; speedup vs baseline: 2.9182x; 1.0808x over previous
//
#include <hip/hip_runtime.h>
#include <math.h>

#define IN_C   128
#define OUT_C  64
#define CDIM   512
#define HW     128   // input spatial (half-res)
#define PHW    130   // padded
#define OHW    256   // output spatial
#define NB     8     // batch

typedef __attribute__((ext_vector_type(8))) short short8;
typedef __attribute__((ext_vector_type(4))) float f32x4;

__device__ inline unsigned short f2bf(float f) {
    unsigned int u = __float_as_uint(f);
    unsigned int r = (u + 0x7fffu + ((u >> 16) & 1u)) >> 16;
    return (unsigned short)r;
}

__device__ inline float postact(float v) {
    v = v > 0.f ? v : 0.2f * v;
    v *= 1.4142135623730951f;
    return fminf(fmaxf(v, -256.f), 256.f);
}

__device__ __forceinline__ void gload16(const void* g, void* l) {
    __builtin_amdgcn_global_load_lds(
        (const __attribute__((address_space(1))) unsigned int*)g,
        (__attribute__((address_space(3))) unsigned int*)l, 16, 0, 0);
}

// ================= fused prep: wbprep (blocks 0..1151) + border (1152..1409) + gain (1410..1665)
// wb2 layout (A fragment-linear, REGION-MAJOR):
//   flat = kt*16384 + pr*512 + lane*8 + e,  pr = hh*16 + kc*8 + wM*4 + fi
//   holds Wb[m][ic] for m = (wM*8 + hh*4 + fi)*16 + (lane&15),
//                       ic = (kt&1)*64 + kc*32 + (lane>>4)*8 + e,  tap = kt>>1
__global__ __launch_bounds__(256) void prep_kernel(
    const float* __restrict__ w, unsigned short* __restrict__ wb2,
    unsigned short* __restrict__ xg,
    const float* __restrict__ c, const float* __restrict__ wa,
    const float* __restrict__ ba, float* __restrict__ gain) {
    int blk = blockIdx.x;
    if (blk < 1152) {
        int idx  = blk * 256 + threadIdx.x;          // 18*16384 total
        int e    = idx & 7;
        int lane = (idx >> 3) & 63;
        int pr   = (idx >> 9) & 31;
        int kt   = idx >> 14;                        // 0..17
        int hh = pr >> 4, kcb = (pr >> 3) & 1, wM = (pr >> 2) & 1, fi = pr & 3;
        int m   = (wM * 8 + hh * 4 + fi) * 16 + (lane & 15);
        int ic  = (kt & 1) * 64 + kcb * 32 + (lane >> 4) * 8 + e;
        int tap = kt >> 1;
        int ky = tap / 3, kx = tap % 3;
        int oc = m >> 2, ph = m & 3;
        int py = ph >> 1, px = ph & 1;
        int sy = 2 * ky + (py == 0 ? 1 : 0);
        int sx = 2 * kx + (px == 0 ? 1 : 0);
        const float k1[4] = {0.25f, 0.75f, 0.75f, 0.25f};
        float sum = 0.f;
        #pragma unroll
        for (int by = 0; by < 3; ++by) {
            int ay = sy - by;
            if (ay < 0 || ay > 3) continue;
            #pragma unroll
            for (int bx = 0; bx < 3; ++bx) {
                int ax = sx - bx;
                if (ax < 0 || ax > 3) continue;
                sum += w[((oc * IN_C + ic) * 3 + (2 - by)) * 3 + (2 - bx)] * k1[ay] * k1[ax];
            }
        }
        wb2[idx] = f2bf(sum * 0.029462782549439483f);   // 1/sqrt(1152)
    } else if (blk < 1410) {
        int id = (blk - 1152) * 256 + threadIdx.x;   // 8*516*16 = 66048 exact
        int cc = id & 15;
        int t  = id >> 4;
        int p  = t % 516;
        int n  = t / 516;
        int Y, X;
        if (p < 130)      { Y = 0;   X = p; }
        else if (p < 260) { Y = 129; X = p - 130; }
        else              { int q = p - 260; Y = 1 + (q >> 1); X = (q & 1) * 129; }
        uint4 z = make_uint4(0, 0, 0, 0);
        *reinterpret_cast<uint4*>(xg + (((size_t)(n * PHW) + Y) * PHW + X) * 128 + cc * 8) = z;
    } else {
        int wave = (blk - 1410) * 4 + (threadIdx.x >> 6);   // 0..1023
        int lane = threadIdx.x & 63;
        int n  = wave >> 7;
        int ic = wave & 127;
        const float* cp = c + n * CDIM;
        const float* wp = wa + ic * CDIM;
        float s = 0.f;
        #pragma unroll
        for (int k = 0; k < CDIM / 64; ++k) s += cp[lane + 64 * k] * wp[lane + 64 * k];
        #pragma unroll
        for (int off = 32; off > 0; off >>= 1) s += __shfl_down(s, off);
        if (lane == 0) {
            float y = s * 0.04419417382415922f + ba[ic];
            gain[n * IN_C + ic] = 1.0f + tanhf(y);
        }
    }
}

// ---------------- xprep: padded 130x130 NHWC bf16, 16B-chunk order XOR-swizzled by (X&7)
__global__ __launch_bounds__(256) void xprep_kernel(const float* __restrict__ x,
                                                    const float* __restrict__ gain,
                                                    unsigned short* __restrict__ xg) {
    int n = blockIdx.x >> 7;
    int y = blockIdx.x & 127;
    __shared__ unsigned short lds[128][130];
    int tid = threadIdx.x;
    for (int i = tid; i < 128 * 128; i += 256) {
        int ic = i >> 7, pix = i & 127;
        float v = x[(((n * IN_C + ic) * HW) + y) * HW + pix] * gain[n * IN_C + ic];
        lds[pix][ic] = f2bf(v);
    }
    __syncthreads();
    unsigned int* dst = (unsigned int*)(xg + (((size_t)(n * PHW) + y + 1) * PHW + 1) * 128);
    for (int i = tid; i < 8192; i += 256) {
        int pix = i >> 6, d = i & 63;
        int j = d >> 2, ww = d & 3;
        int js = j ^ ((pix + 1) & 7);          // swizzle key = padded X & 7
        dst[pix * 64 + js * 4 + ww] = *reinterpret_cast<const unsigned int*>(&lds[pix][d * 2]);
    }
}

// ---------------- main conv: M=256 x N=256px x K=1152.
// B halo (18x18x128 bf16 = 83KB) LDS-resident. A AND B register-double-buffered one
// half-K-step ahead, ROLLED 18-iter loop (small icache footprint).
// No K-loop barriers; compiler-counted vmcnt/lgkmcnt; 2 waves/SIMD by design.
#define MM(ACC, AF, BF) ACC = __builtin_amdgcn_mfma_f32_16x16x32_bf16(AF, BF, ACC, 0, 0, 0)

__global__ __launch_bounds__(512, 2) void conv_mfma9(
    const unsigned short* __restrict__ xg,
    const unsigned short* __restrict__ wb2,
    const float* __restrict__ bias,
    float* __restrict__ out) {
    __shared__ __align__(16) char haloB[82944];   // 18 rows x 18 px x 256B

    const int bid = blockIdx.x;                 // 512 blocks; bijective XCD swizzle (512%8==0)
    const int wg  = ((bid & 7) << 6) + (bid >> 3);
    const int n     = wg >> 6;
    const int patch = wg & 63;
    const int Y0 = (patch >> 3) * 16;
    const int X0 = (patch & 7) * 16;            // mult of 8 -> swizzle key block-independent
    const int tid  = threadIdx.x;
    const int lane = tid & 63;
    const int wid  = tid >> 6;
    const int wM = wid & 1;                     // SIMD-cohabiting waves (wid, wid+4) share wM
    const int wN = wid >> 1;                    // 0..3
    const int l16 = lane & 15;
    const int lhi = lane >> 4;
    const int pbase = wN * 4;

    const char* xgb = (const char*)xg + (size_t)n * PHW * PHW * 256;

    // ---- stage B halo once: 18 rows x 18 px x 256B = 5184 chunks of 16B, linear LDS
    #pragma unroll 1
    for (int i = 0; i < 11; ++i) {
        int cc = i * 512 + tid;
        if (cc < 5184) {
            int r = cc / 288;
            int t2 = cc - r * 288;
            gload16(xgb + ((size_t)(Y0 + r) * PHW + X0) * 256 + t2 * 16,
                    haloB + (i * 512 + wid * 64) * 16);
        }
    }

    // per-lane A base: frag f of (t,kc) lives at
    //   abase + t*32768 + kc*8192 + ((f>>2)*16 + (f&3))*1024
    const char* abase = (const char*)wb2 + (wM << 12) + (lane << 4);

    f32x4 acc[8][4];
    #pragma unroll
    for (int f = 0; f < 8; ++f)
        #pragma unroll
        for (int b = 0; b < 4; ++b) acc[f][b] = (f32x4)0.f;

    __syncthreads();   // halo resident for all waves (drains vmcnt before barrier)

    short8 Aa[8], Ab[8], Ba[4], Bb[4];

    auto loadA = [&](short8 (&A)[8], int t, int kc) {
        const char* ak = abase + t * 32768 + kc * 8192;
        #pragma unroll
        for (int f = 0; f < 8; ++f)
            A[f] = *reinterpret_cast<const short8*>(ak + ((((f >> 2) << 4) + (f & 3)) << 10));
    };
    // rowb = (pbase+ky)*18 + C ; off folds h,kc,lhi and the X-swizzle
    auto loadB = [&](short8 (&B)[4], int rowb, int off) {
        #pragma unroll
        for (int b = 0; b < 4; ++b)
            B[b] = *reinterpret_cast<const short8*>(haloB + ((rowb + b * 18) << 8) + off);
    };
    auto cluster = [&](short8 (&A)[8], short8 (&B)[4]) {
        __builtin_amdgcn_s_setprio(1);
        #pragma unroll
        for (int f = 0; f < 8; ++f)
            #pragma unroll
            for (int b = 0; b < 4; ++b) MM(acc[f][b], A[f], B[b]);
        __builtin_amdgcn_s_setprio(0);
    };

    // prime (t=0: ky=0, kx=0, h=0, kc=0)
    loadA(Aa, 0, 0);
    {
        const int C0 = l16;
        loadB(Ba, pbase * 18 + C0, (lhi << 4) ^ ((C0 & 7) << 4));
    }

    #pragma unroll 1
    for (int t = 0; t < 18; ++t) {
        const int tap = t >> 1;
        const int h   = t & 1;
        const int ky  = tap / 3;
        const int kx  = tap - ky * 3;
        const int C   = l16 + kx;
        const int bswz = (C & 7) << 4;
        const int rowb = (pbase + ky) * 18 + C;

        // ===== half kc=0: prefetch (t, kc=1); cluster on (t, kc=0)
        loadA(Ab, t, 1);
        loadB(Bb, rowb, ((h << 7) + 64 + (lhi << 4)) ^ bswz);
        __builtin_amdgcn_sched_barrier(0);
        cluster(Aa, Ba);

        // ===== half kc=1: prefetch (t+1, kc=0); cluster on (t, kc=1)
        if (t + 1 < 18) {
            const int t1   = t + 1;
            const int tap1 = t1 >> 1;
            const int h1   = t1 & 1;
            const int ky1  = tap1 / 3;
            const int kx1  = tap1 - ky1 * 3;
            const int C1   = l16 + kx1;
            loadA(Aa, t1, 0);
            loadB(Ba, (pbase + ky1) * 18 + C1,
                  ((h1 << 7) + (lhi << 4)) ^ ((C1 & 7) << 4));
        }
        __builtin_amdgcn_sched_barrier(0);
        cluster(Ab, Bb);
    }

    // ---- epilogue: M = wM*128 + f*16 + lhi*4 + r ; oc = M>>2, phase = M&3 = r
    #pragma unroll
    for (int f = 0; f < 8; ++f) {
        const int oc = wM * 32 + f * 4 + lhi;
        const float bi = bias[oc];
        #pragma unroll
        for (int b = 0; b < 4; ++b) {
            const int ypix = Y0 + pbase + b;
            const int xpix = X0 + l16;
            float* o0 = out + (((size_t)(n * OUT_C + oc) * OHW) + 2 * ypix) * OHW + 2 * xpix;
            float2 v0 = make_float2(postact(acc[f][b][0] + bi), postact(acc[f][b][1] + bi));
            float2 v1 = make_float2(postact(acc[f][b][2] + bi), postact(acc[f][b][3] + bi));
            *reinterpret_cast<float2*>(o0) = v0;
            *reinterpret_cast<float2*>(o0 + OHW) = v1;
        }
    }
}

// ================= fallback f32 path (round-1, verified) =================
__global__ void gain_kernel(const float* __restrict__ c,
                            const float* __restrict__ w_affine,
                            const float* __restrict__ b_affine,
                            float* __restrict__ gain) {
    int wave = (blockIdx.x * blockDim.x + threadIdx.x) >> 6;
    int lane = threadIdx.x & 63;
    if (wave >= NB * IN_C) return;
    int n  = wave >> 7;
    int ic = wave & 127;
    const float* cp = c + n * CDIM;
    const float* wp = w_affine + ic * CDIM;
    float s = 0.f;
    #pragma unroll
    for (int k = 0; k < CDIM / 64; ++k) s += cp[lane + 64 * k] * wp[lane + 64 * k];
    #pragma unroll
    for (int off = 32; off > 0; off >>= 1) s += __shfl_down(s, off);
    if (lane == 0) {
        float y = s * 0.04419417382415922f + b_affine[ic];
        gain[n * IN_C + ic] = 1.0f + tanhf(y);
    }
}

__global__ void wprep_kernel(const float* __restrict__ w, float* __restrict__ wp) {
    int idx = blockIdx.x * blockDim.x + threadIdx.x;
    if (idx >= IN_C * 9 * 4 * OUT_C) return;
    int oc = idx & 63;
    int t  = idx >> 6;
    int ph = t & 3;  t >>= 2;
    int kx = t % 3;  t /= 3;
    int ky = t % 3;  t /= 3;
    int ic = t;
    int py = ph >> 1, px = ph & 1;
    int sy = 2 * ky + (py == 0 ? 1 : 0);
    int sx = 2 * kx + (px == 0 ? 1 : 0);
    const float k1[4] = {0.25f, 0.75f, 0.75f, 0.25f};
    float sum = 0.f;
    #pragma unroll
    for (int by = 0; by < 3; ++by) {
        int ay = sy - by;
        if (ay < 0 || ay > 3) continue;
        #pragma unroll
        for (int bx = 0; bx < 3; ++bx) {
            int ax = sx - bx;
            if (ax < 0 || ax > 3) continue;
            sum += w[((oc * IN_C + ic) * 3 + (2 - by)) * 3 + (2 - bx)] * k1[ay] * k1[ax];
        }
    }
    wp[idx] = sum * 0.029462782549439483f;
}

__global__ __launch_bounds__(256) void conv_main(
    const float* __restrict__ x, const float* __restrict__ gain,
    const float* __restrict__ wp, const float* __restrict__ bias,
    float* __restrict__ out) {
    const int n    = blockIdx.z >> 3;
    const int occ  = (blockIdx.z & 7) * 8;
    const int tx0  = blockIdx.x * 16;
    const int ty0  = blockIdx.y * 16;
    const int tid  = threadIdx.x;
    const int lx   = tid & 15;
    const int ly   = tid >> 4;
    __shared__ float xsf[8][18][18];
    float acc[4][8];
    #pragma unroll
    for (int p = 0; p < 4; ++p)
        #pragma unroll
        for (int o = 0; o < 8; ++o) acc[p][o] = 0.f;
    for (int ic0 = 0; ic0 < IN_C; ic0 += 8) {
        __syncthreads();
        for (int i = tid; i < 8 * 324; i += 256) {
            int icb = i / 324;
            int rem = i - icb * 324;
            int yy  = rem / 18;
            int xx  = rem - yy * 18;
            int gy  = ty0 + yy - 1;
            int gx  = tx0 + xx - 1;
            int ic  = ic0 + icb;
            float v = 0.f;
            if (gy >= 0 && gy < HW && gx >= 0 && gx < HW)
                v = x[((n * IN_C + ic) * HW + gy) * HW + gx] * gain[n * IN_C + ic];
            xsf[icb][yy][xx] = v;
        }
        __syncthreads();
        for (int icb = 0; icb < 8; ++icb) {
            const int ic = ic0 + icb;
            const float* wpp = wp + ic * (9 * 4 * OUT_C) + occ;
            #pragma unroll
            for (int ky = 0; ky < 3; ++ky)
                #pragma unroll
                for (int kx = 0; kx < 3; ++kx) {
                    float tv = xsf[icb][ly + ky][lx + kx];
                    const float* w9 = wpp + (ky * 3 + kx) * (4 * OUT_C);
                    #pragma unroll
                    for (int p = 0; p < 4; ++p)
                        #pragma unroll
                        for (int o = 0; o < 8; ++o)
                            acc[p][o] = fmaf(tv, w9[p * OUT_C + o], acc[p][o]);
                }
        }
    }
    const int ybase = 2 * (ty0 + ly);
    const int xbase = 2 * (tx0 + lx);
    #pragma unroll
    for (int o = 0; o < 8; ++o) {
        float b = bias[occ + o];
        #pragma unroll
        for (int py = 0; py < 2; ++py) {
            float2 v;
            v.x = postact(acc[py * 2 + 0][o] + b);
            v.y = postact(acc[py * 2 + 1][o] + b);
            *reinterpret_cast<float2*>(
                &out[((size_t)(n * OUT_C + occ + o) * OHW + (ybase + py)) * OHW + xbase]) = v;
        }
    }
}

extern "C" void kernel_launch(void* const* d_in, const int* in_sizes, int n_in,
                              void* d_out, int out_size, void* d_ws, size_t ws_size,
                              hipStream_t stream) {
    const float* x        = (const float*)d_in[0];
    const float* c        = (const float*)d_in[1];
    const float* weight   = (const float*)d_in[2];
    const float* bias     = (const float*)d_in[3];
    const float* w_affine = (const float*)d_in[4];
    const float* b_affine = (const float*)d_in[5];
    float* out = (float*)d_out;

    float* gain = (float*)d_ws;   // 4 KB @ 0

    const size_t NEED = 1048576 + (size_t)NB * PHW * PHW * IN_C * 2;  // ~35.7 MB
    if (ws_size >= NEED) {
        unsigned short* wb2 = (unsigned short*)((char*)d_ws + 8192);      // 589824 B
        unsigned short* xg  = (unsigned short*)((char*)d_ws + 1048576);   // 34.6 MB padded+swizzled NHWC
        prep_kernel<<<dim3(1666), dim3(256), 0, stream>>>(weight, wb2, xg, c, w_affine, b_affine, gain);
        xprep_kernel<<<dim3(NB * HW), dim3(256), 0, stream>>>(x, gain, xg);
        conv_mfma9<<<dim3(512), dim3(512), 0, stream>>>(xg, wb2, bias, out);
    } else {
        float* wp = (float*)((char*)d_ws + 8192);
        gain_kernel<<<dim3((NB * IN_C * 64) / 256), dim3(256), 0, stream>>>(c, w_affine, b_affine, gain);
        wprep_kernel<<<dim3((IN_C * 9 * 4 * OUT_C + 255) / 256), dim3(256), 0, stream>>>(weight, wp);
        conv_main<<<dim3(HW / 16, HW / 16, NB * 8), dim3(256), 0, stream>>>(x, gain, wp, bias, out);
    }
}

// Round 11
// 100.945 us; speedup vs baseline: 2.9989x; 1.0276x over previous
//
#include <hip/hip_runtime.h>
#include <math.h>

#define IN_C   128
#define OUT_C  64
#define CDIM   512
#define HW     128   // input spatial (half-res)
#define PHW    130   // padded
#define OHW    256   // output spatial
#define NB     8     // batch

typedef __attribute__((ext_vector_type(8))) short short8;
typedef __attribute__((ext_vector_type(4))) float f32x4;

__device__ inline unsigned short f2bf(float f) {
    unsigned int u = __float_as_uint(f);
    unsigned int r = (u + 0x7fffu + ((u >> 16) & 1u)) >> 16;
    return (unsigned short)r;
}

__device__ inline float postact(float v) {
    v = v > 0.f ? v : 0.2f * v;
    v *= 1.4142135623730951f;
    return fminf(fmaxf(v, -256.f), 256.f);
}

__device__ __forceinline__ void gload16(const void* g, void* l) {
    __builtin_amdgcn_global_load_lds(
        (const __attribute__((address_space(1))) unsigned int*)g,
        (__attribute__((address_space(3))) unsigned int*)l, 16, 0, 0);
}

// ================= fused prep: wbprep (blocks 0..1151) + border (1152..1409) + gain (1410..1665)
// wb2 layout (A fragment-linear, REGION-MAJOR):
//   flat = kt*16384 + pr*512 + lane*8 + e,  pr = hh*16 + kc*8 + wM*4 + fi
//   holds Wb[m][ic] for m = (wM*8 + hh*4 + fi)*16 + (lane&15),
//                       ic = (kt&1)*64 + kc*32 + (lane>>4)*8 + e,  tap = kt>>1
__global__ __launch_bounds__(256) void prep_kernel(
    const float* __restrict__ w, unsigned short* __restrict__ wb2,
    unsigned short* __restrict__ xg,
    const float* __restrict__ c, const float* __restrict__ wa,
    const float* __restrict__ ba, float* __restrict__ gain) {
    int blk = blockIdx.x;
    if (blk < 1152) {
        int idx  = blk * 256 + threadIdx.x;          // 18*16384 total
        int e    = idx & 7;
        int lane = (idx >> 3) & 63;
        int pr   = (idx >> 9) & 31;
        int kt   = idx >> 14;                        // 0..17
        int hh = pr >> 4, kcb = (pr >> 3) & 1, wM = (pr >> 2) & 1, fi = pr & 3;
        int m   = (wM * 8 + hh * 4 + fi) * 16 + (lane & 15);
        int ic  = (kt & 1) * 64 + kcb * 32 + (lane >> 4) * 8 + e;
        int tap = kt >> 1;
        int ky = tap / 3, kx = tap % 3;
        int oc = m >> 2, ph = m & 3;
        int py = ph >> 1, px = ph & 1;
        int sy = 2 * ky + (py == 0 ? 1 : 0);
        int sx = 2 * kx + (px == 0 ? 1 : 0);
        const float k1[4] = {0.25f, 0.75f, 0.75f, 0.25f};
        float sum = 0.f;
        #pragma unroll
        for (int by = 0; by < 3; ++by) {
            int ay = sy - by;
            if (ay < 0 || ay > 3) continue;
            #pragma unroll
            for (int bx = 0; bx < 3; ++bx) {
                int ax = sx - bx;
                if (ax < 0 || ax > 3) continue;
                sum += w[((oc * IN_C + ic) * 3 + (2 - by)) * 3 + (2 - bx)] * k1[ay] * k1[ax];
            }
        }
        wb2[idx] = f2bf(sum * 0.029462782549439483f);   // 1/sqrt(1152)
    } else if (blk < 1410) {
        int id = (blk - 1152) * 256 + threadIdx.x;   // 8*516*16 = 66048 exact
        int cc = id & 15;
        int t  = id >> 4;
        int p  = t % 516;
        int n  = t / 516;
        int Y, X;
        if (p < 130)      { Y = 0;   X = p; }
        else if (p < 260) { Y = 129; X = p - 130; }
        else              { int q = p - 260; Y = 1 + (q >> 1); X = (q & 1) * 129; }
        uint4 z = make_uint4(0, 0, 0, 0);
        *reinterpret_cast<uint4*>(xg + (((size_t)(n * PHW) + Y) * PHW + X) * 128 + cc * 8) = z;
    } else {
        int wave = (blk - 1410) * 4 + (threadIdx.x >> 6);   // 0..1023
        int lane = threadIdx.x & 63;
        int n  = wave >> 7;
        int ic = wave & 127;
        const float* cp = c + n * CDIM;
        const float* wp = wa + ic * CDIM;
        float s = 0.f;
        #pragma unroll
        for (int k = 0; k < CDIM / 64; ++k) s += cp[lane + 64 * k] * wp[lane + 64 * k];
        #pragma unroll
        for (int off = 32; off > 0; off >>= 1) s += __shfl_down(s, off);
        if (lane == 0) {
            float y = s * 0.04419417382415922f + ba[ic];
            gain[n * IN_C + ic] = 1.0f + tanhf(y);
        }
    }
}

// ---------------- xprep: padded 130x130 NHWC bf16, 16B-chunk order XOR-swizzled by (X&7)
__global__ __launch_bounds__(256) void xprep_kernel(const float* __restrict__ x,
                                                    const float* __restrict__ gain,
                                                    unsigned short* __restrict__ xg) {
    int n = blockIdx.x >> 7;
    int y = blockIdx.x & 127;
    __shared__ unsigned short lds[128][130];
    int tid = threadIdx.x;
    for (int i = tid; i < 128 * 128; i += 256) {
        int ic = i >> 7, pix = i & 127;
        float v = x[(((n * IN_C + ic) * HW) + y) * HW + pix] * gain[n * IN_C + ic];
        lds[pix][ic] = f2bf(v);
    }
    __syncthreads();
    unsigned int* dst = (unsigned int*)(xg + (((size_t)(n * PHW) + y + 1) * PHW + 1) * 128);
    for (int i = tid; i < 8192; i += 256) {
        int pix = i >> 6, d = i & 63;
        int j = d >> 2, ww = d & 3;
        int js = j ^ ((pix + 1) & 7);          // swizzle key = padded X & 7
        dst[pix * 64 + js * 4 + ww] = *reinterpret_cast<const unsigned int*>(&lds[pix][d * 2]);
    }
}

// ---------------- main conv: M=256 x N=256px x K=1152.
// B halo (18x18x128 bf16 = 83KB) LDS-resident. A AND B register-double-buffered one
// half-K-step ahead, ROLLED 18-iter loop. Wave tile re-shaped 4M x 8N frags:
// halves per-wave A L1 traffic (4KB/half-step) vs R10; MFMA/wave unchanged (32).
// No K-loop barriers; compiler-counted vmcnt/lgkmcnt; 2 waves/SIMD by design.
#define MM(ACC, AF, BF) ACC = __builtin_amdgcn_mfma_f32_16x16x32_bf16(AF, BF, ACC, 0, 0, 0)

__global__ __launch_bounds__(512, 2) void conv_mfma10(
    const unsigned short* __restrict__ xg,
    const unsigned short* __restrict__ wb2,
    const float* __restrict__ bias,
    float* __restrict__ out) {
    __shared__ __align__(16) char haloB[82944];   // 18 rows x 18 px x 256B

    const int bid = blockIdx.x;                 // 512 blocks; bijective XCD swizzle (512%8==0)
    const int wg  = ((bid & 7) << 6) + (bid >> 3);
    const int n     = wg >> 6;
    const int patch = wg & 63;
    const int Y0 = (patch >> 3) * 16;
    const int X0 = (patch & 7) * 16;            // mult of 8 -> swizzle key block-independent
    const int tid  = threadIdx.x;
    const int lane = tid & 63;
    const int wid  = tid >> 6;
    const int q  = wid & 3;                     // M-quarter; SIMD-cohabitants (wid, wid+4) share q
    const int wN = wid >> 2;                    // 0..1 -> 8 pixel-rows each
    const int l16 = lane & 15;
    const int lhi = lane >> 4;
    const int pbase = wN * 8;

    const char* xgb = (const char*)xg + (size_t)n * PHW * PHW * 256;

    // ---- stage B halo once: 18 rows x 18 px x 256B = 5184 chunks of 16B, linear LDS
    #pragma unroll 1
    for (int i = 0; i < 11; ++i) {
        int cc = i * 512 + tid;
        if (cc < 5184) {
            int r = cc / 288;
            int t2 = cc - r * 288;
            gload16(xgb + ((size_t)(Y0 + r) * PHW + X0) * 256 + t2 * 16,
                    haloB + (i * 512 + wid * 64) * 16);
        }
    }

    // per-lane A base for M-quarter q (wMold = q&1, hh = q>>1):
    //   frag f of (t,kc) at abase + t*32768 + kc*8192 + f*1024
    const char* abase = (const char*)wb2 + ((q >> 1) << 14) + ((q & 1) << 12) + (lane << 4);

    f32x4 acc[4][8];
    #pragma unroll
    for (int f = 0; f < 4; ++f)
        #pragma unroll
        for (int b = 0; b < 8; ++b) acc[f][b] = (f32x4)0.f;

    __syncthreads();   // halo resident for all waves (drains vmcnt before barrier)

    short8 Aa[4], Ab[4], Ba[8], Bb[8];

    auto loadA = [&](short8 (&A)[4], int t, int kc) {
        const char* ak = abase + t * 32768 + kc * 8192;
        #pragma unroll
        for (int f = 0; f < 4; ++f)
            A[f] = *reinterpret_cast<const short8*>(ak + (f << 10));
    };
    // rowb = (pbase+ky)*18 + C ; off folds h,kc,lhi and the X-swizzle
    auto loadB = [&](short8 (&B)[8], int rowb, int off) {
        #pragma unroll
        for (int b = 0; b < 8; ++b)
            B[b] = *reinterpret_cast<const short8*>(haloB + ((rowb + b * 18) << 8) + off);
    };
    auto cluster = [&](short8 (&A)[4], short8 (&B)[8]) {
        __builtin_amdgcn_s_setprio(1);
        #pragma unroll
        for (int f = 0; f < 4; ++f)
            #pragma unroll
            for (int b = 0; b < 8; ++b) MM(acc[f][b], A[f], B[b]);
        __builtin_amdgcn_s_setprio(0);
    };

    // prime (t=0: ky=0, kx=0, h=0, kc=0)
    loadA(Aa, 0, 0);
    {
        const int C0 = l16;
        loadB(Ba, pbase * 18 + C0, (lhi << 4) ^ ((C0 & 7) << 4));
    }

    #pragma unroll 1
    for (int t = 0; t < 18; ++t) {
        const int tap = t >> 1;
        const int h   = t & 1;
        const int ky  = tap / 3;
        const int kx  = tap - ky * 3;
        const int C   = l16 + kx;
        const int bswz = (C & 7) << 4;
        const int rowb = (pbase + ky) * 18 + C;

        // ===== half kc=0: prefetch (t, kc=1); cluster on (t, kc=0)
        loadA(Ab, t, 1);
        loadB(Bb, rowb, ((h << 7) + 64 + (lhi << 4)) ^ bswz);
        __builtin_amdgcn_sched_barrier(0);
        cluster(Aa, Ba);

        // ===== half kc=1: prefetch (t+1, kc=0); cluster on (t, kc=1)
        if (t + 1 < 18) {
            const int t1   = t + 1;
            const int tap1 = t1 >> 1;
            const int h1   = t1 & 1;
            const int ky1  = tap1 / 3;
            const int kx1  = tap1 - ky1 * 3;
            const int C1   = l16 + kx1;
            loadA(Aa, t1, 0);
            loadB(Ba, (pbase + ky1) * 18 + C1,
                  ((h1 << 7) + (lhi << 4)) ^ ((C1 & 7) << 4));
        }
        __builtin_amdgcn_sched_barrier(0);
        cluster(Ab, Bb);
    }

    // ---- epilogue: M = (q&1)*128 + (q>>1)*64 + f*16 + lhi*4 + r ; oc = M>>2, phase = r
    #pragma unroll
    for (int f = 0; f < 4; ++f) {
        const int oc = (q & 1) * 32 + (q >> 1) * 16 + f * 4 + lhi;
        const float bi = bias[oc];
        #pragma unroll
        for (int b = 0; b < 8; ++b) {
            const int ypix = Y0 + pbase + b;
            const int xpix = X0 + l16;
            float* o0 = out + (((size_t)(n * OUT_C + oc) * OHW) + 2 * ypix) * OHW + 2 * xpix;
            float2 v0 = make_float2(postact(acc[f][b][0] + bi), postact(acc[f][b][1] + bi));
            float2 v1 = make_float2(postact(acc[f][b][2] + bi), postact(acc[f][b][3] + bi));
            *reinterpret_cast<float2*>(o0) = v0;
            *reinterpret_cast<float2*>(o0 + OHW) = v1;
        }
    }
}

// ================= fallback f32 path (round-1, verified) =================
__global__ void gain_kernel(const float* __restrict__ c,
                            const float* __restrict__ w_affine,
                            const float* __restrict__ b_affine,
                            float* __restrict__ gain) {
    int wave = (blockIdx.x * blockDim.x + threadIdx.x) >> 6;
    int lane = threadIdx.x & 63;
    if (wave >= NB * IN_C) return;
    int n  = wave >> 7;
    int ic = wave & 127;
    const float* cp = c + n * CDIM;
    const float* wp = w_affine + ic * CDIM;
    float s = 0.f;
    #pragma unroll
    for (int k = 0; k < CDIM / 64; ++k) s += cp[lane + 64 * k] * wp[lane + 64 * k];
    #pragma unroll
    for (int off = 32; off > 0; off >>= 1) s += __shfl_down(s, off);
    if (lane == 0) {
        float y = s * 0.04419417382415922f + b_affine[ic];
        gain[n * IN_C + ic] = 1.0f + tanhf(y);
    }
}

__global__ void wprep_kernel(const float* __restrict__ w, float* __restrict__ wp) {
    int idx = blockIdx.x * blockDim.x + threadIdx.x;
    if (idx >= IN_C * 9 * 4 * OUT_C) return;
    int oc = idx & 63;
    int t  = idx >> 6;
    int ph = t & 3;  t >>= 2;
    int kx = t % 3;  t /= 3;
    int ky = t % 3;  t /= 3;
    int ic = t;
    int py = ph >> 1, px = ph & 1;
    int sy = 2 * ky + (py == 0 ? 1 : 0);
    int sx = 2 * kx + (px == 0 ? 1 : 0);
    const float k1[4] = {0.25f, 0.75f, 0.75f, 0.25f};
    float sum = 0.f;
    #pragma unroll
    for (int by = 0; by < 3; ++by) {
        int ay = sy - by;
        if (ay < 0 || ay > 3) continue;
        #pragma unroll
        for (int bx = 0; bx < 3; ++bx) {
            int ax = sx - bx;
            if (ax < 0 || ax > 3) continue;
            sum += w[((oc * IN_C + ic) * 3 + (2 - by)) * 3 + (2 - bx)] * k1[ay] * k1[ax];
        }
    }
    wp[idx] = sum * 0.029462782549439483f;
}

__global__ __launch_bounds__(256) void conv_main(
    const float* __restrict__ x, const float* __restrict__ gain,
    const float* __restrict__ wp, const float* __restrict__ bias,
    float* __restrict__ out) {
    const int n    = blockIdx.z >> 3;
    const int occ  = (blockIdx.z & 7) * 8;
    const int tx0  = blockIdx.x * 16;
    const int ty0  = blockIdx.y * 16;
    const int tid  = threadIdx.x;
    const int lx   = tid & 15;
    const int ly   = tid >> 4;
    __shared__ float xsf[8][18][18];
    float acc[4][8];
    #pragma unroll
    for (int p = 0; p < 4; ++p)
        #pragma unroll
        for (int o = 0; o < 8; ++o) acc[p][o] = 0.f;
    for (int ic0 = 0; ic0 < IN_C; ic0 += 8) {
        __syncthreads();
        for (int i = tid; i < 8 * 324; i += 256) {
            int icb = i / 324;
            int rem = i - icb * 324;
            int yy  = rem / 18;
            int xx  = rem - yy * 18;
            int gy  = ty0 + yy - 1;
            int gx  = tx0 + xx - 1;
            int ic  = ic0 + icb;
            float v = 0.f;
            if (gy >= 0 && gy < HW && gx >= 0 && gx < HW)
                v = x[((n * IN_C + ic) * HW + gy) * HW + gx] * gain[n * IN_C + ic];
            xsf[icb][yy][xx] = v;
        }
        __syncthreads();
        for (int icb = 0; icb < 8; ++icb) {
            const int ic = ic0 + icb;
            const float* wpp = wp + ic * (9 * 4 * OUT_C) + occ;
            #pragma unroll
            for (int ky = 0; ky < 3; ++ky)
                #pragma unroll
                for (int kx = 0; kx < 3; ++kx) {
                    float tv = xsf[icb][ly + ky][lx + kx];
                    const float* w9 = wpp + (ky * 3 + kx) * (4 * OUT_C);
                    #pragma unroll
                    for (int p = 0; p < 4; ++p)
                        #pragma unroll
                        for (int o = 0; o < 8; ++o)
                            acc[p][o] = fmaf(tv, w9[p * OUT_C + o], acc[p][o]);
                }
        }
    }
    const int ybase = 2 * (ty0 + ly);
    const int xbase = 2 * (tx0 + lx);
    #pragma unroll
    for (int o = 0; o < 8; ++o) {
        float b = bias[occ + o];
        #pragma unroll
        for (int py = 0; py < 2; ++py) {
            float2 v;
            v.x = postact(acc[py * 2 + 0][o] + b);
            v.y = postact(acc[py * 2 + 1][o] + b);
            *reinterpret_cast<float2*>(
                &out[((size_t)(n * OUT_C + occ + o) * OHW + (ybase + py)) * OHW + xbase]) = v;
        }
    }
}

extern "C" void kernel_launch(void* const* d_in, const int* in_sizes, int n_in,
                              void* d_out, int out_size, void* d_ws, size_t ws_size,
                              hipStream_t stream) {
    const float* x        = (const float*)d_in[0];
    const float* c        = (const float*)d_in[1];
    const float* weight   = (const float*)d_in[2];
    const float* bias     = (const float*)d_in[3];
    const float* w_affine = (const float*)d_in[4];
    const float* b_affine = (const float*)d_in[5];
    float* out = (float*)d_out;

    float* gain = (float*)d_ws;   // 4 KB @ 0

    const size_t NEED = 1048576 + (size_t)NB * PHW * PHW * IN_C * 2;  // ~35.7 MB
    if (ws_size >= NEED) {
        unsigned short* wb2 = (unsigned short*)((char*)d_ws + 8192);      // 589824 B
        unsigned short* xg  = (unsigned short*)((char*)d_ws + 1048576);   // 34.6 MB padded+swizzled NHWC
        prep_kernel<<<dim3(1666), dim3(256), 0, stream>>>(weight, wb2, xg, c, w_affine, b_affine, gain);
        xprep_kernel<<<dim3(NB * HW), dim3(256), 0, stream>>>(x, gain, xg);
        conv_mfma10<<<dim3(512), dim3(512), 0, stream>>>(xg, wb2, bias, out);
    } else {
        float* wp = (float*)((char*)d_ws + 8192);
        gain_kernel<<<dim3((NB * IN_C * 64) / 256), dim3(256), 0, stream>>>(c, w_affine, b_affine, gain);
        wprep_kernel<<<dim3((IN_C * 9 * 4 * OUT_C + 255) / 256), dim3(256), 0, stream>>>(weight, wp);
        conv_main<<<dim3(HW / 16, HW / 16, NB * 8), dim3(256), 0, stream>>>(x, gain, wp, bias, out);
    }
}

// Round 12
// 100.332 us; speedup vs baseline: 3.0172x; 1.0061x over previous
//
#include <hip/hip_runtime.h>
#include <math.h>

#define IN_C   128
#define OUT_C  64
#define CDIM   512
#define HW     128   // input spatial (half-res)
#define PHW    130   // padded
#define OHW    256   // output spatial
#define NB     8     // batch

typedef __attribute__((ext_vector_type(8))) short short8;
typedef __attribute__((ext_vector_type(4))) float f32x4;

__device__ inline unsigned short f2bf(float f) {
    unsigned int u = __float_as_uint(f);
    unsigned int r = (u + 0x7fffu + ((u >> 16) & 1u)) >> 16;
    return (unsigned short)r;
}

__device__ inline float postact(float v) {
    v = v > 0.f ? v : 0.2f * v;
    v *= 1.4142135623730951f;
    return fminf(fmaxf(v, -256.f), 256.f);
}

__device__ __forceinline__ void gload16(const void* g, void* l) {
    __builtin_amdgcn_global_load_lds(
        (const __attribute__((address_space(1))) unsigned int*)g,
        (__attribute__((address_space(3))) unsigned int*)l, 16, 0, 0);
}

// ================= fused prep: wbprep (blocks 0..1151) + border (1152..1409) + gain (1410..1665)
// wb2 layout (A fragment-linear, REGION-MAJOR):
//   flat = kt*16384 + pr*512 + lane*8 + e,  pr = hh*16 + kc*8 + wM*4 + fi
//   holds Wb[m][ic] for m = (wM*8 + hh*4 + fi)*16 + (lane&15),
//                       ic = (kt&1)*64 + kc*32 + (lane>>4)*8 + e,  tap = kt>>1
__global__ __launch_bounds__(256) void prep_kernel(
    const float* __restrict__ w, unsigned short* __restrict__ wb2,
    unsigned short* __restrict__ xg,
    const float* __restrict__ c, const float* __restrict__ wa,
    const float* __restrict__ ba, float* __restrict__ gain) {
    int blk = blockIdx.x;
    if (blk < 1152) {
        int idx  = blk * 256 + threadIdx.x;          // 18*16384 total
        int e    = idx & 7;
        int lane = (idx >> 3) & 63;
        int pr   = (idx >> 9) & 31;
        int kt   = idx >> 14;                        // 0..17
        int hh = pr >> 4, kcb = (pr >> 3) & 1, wM = (pr >> 2) & 1, fi = pr & 3;
        int m   = (wM * 8 + hh * 4 + fi) * 16 + (lane & 15);
        int ic  = (kt & 1) * 64 + kcb * 32 + (lane >> 4) * 8 + e;
        int tap = kt >> 1;
        int ky = tap / 3, kx = tap % 3;
        int oc = m >> 2, ph = m & 3;
        int py = ph >> 1, px = ph & 1;
        int sy = 2 * ky + (py == 0 ? 1 : 0);
        int sx = 2 * kx + (px == 0 ? 1 : 0);
        const float k1[4] = {0.25f, 0.75f, 0.75f, 0.25f};
        float sum = 0.f;
        #pragma unroll
        for (int by = 0; by < 3; ++by) {
            int ay = sy - by;
            if (ay < 0 || ay > 3) continue;
            #pragma unroll
            for (int bx = 0; bx < 3; ++bx) {
                int ax = sx - bx;
                if (ax < 0 || ax > 3) continue;
                sum += w[((oc * IN_C + ic) * 3 + (2 - by)) * 3 + (2 - bx)] * k1[ay] * k1[ax];
            }
        }
        wb2[idx] = f2bf(sum * 0.029462782549439483f);   // 1/sqrt(1152)
    } else if (blk < 1410) {
        int id = (blk - 1152) * 256 + threadIdx.x;   // 8*516*16 = 66048 exact
        int cc = id & 15;
        int t  = id >> 4;
        int p  = t % 516;
        int n  = t / 516;
        int Y, X;
        if (p < 130)      { Y = 0;   X = p; }
        else if (p < 260) { Y = 129; X = p - 130; }
        else              { int q = p - 260; Y = 1 + (q >> 1); X = (q & 1) * 129; }
        uint4 z = make_uint4(0, 0, 0, 0);
        *reinterpret_cast<uint4*>(xg + (((size_t)(n * PHW) + Y) * PHW + X) * 128 + cc * 8) = z;
    } else {
        int wave = (blk - 1410) * 4 + (threadIdx.x >> 6);   // 0..1023
        int lane = threadIdx.x & 63;
        int n  = wave >> 7;
        int ic = wave & 127;
        const float* cp = c + n * CDIM;
        const float* wp = wa + ic * CDIM;
        float s = 0.f;
        #pragma unroll
        for (int k = 0; k < CDIM / 64; ++k) s += cp[lane + 64 * k] * wp[lane + 64 * k];
        #pragma unroll
        for (int off = 32; off > 0; off >>= 1) s += __shfl_down(s, off);
        if (lane == 0) {
            float y = s * 0.04419417382415922f + ba[ic];
            gain[n * IN_C + ic] = 1.0f + tanhf(y);
        }
    }
}

// ---------------- xprep: padded 130x130 NHWC bf16, 16B-chunk order XOR-swizzled by (X&7)
__global__ __launch_bounds__(256) void xprep_kernel(const float* __restrict__ x,
                                                    const float* __restrict__ gain,
                                                    unsigned short* __restrict__ xg) {
    int n = blockIdx.x >> 7;
    int y = blockIdx.x & 127;
    __shared__ unsigned short lds[128][130];
    int tid = threadIdx.x;
    for (int i = tid; i < 128 * 128; i += 256) {
        int ic = i >> 7, pix = i & 127;
        float v = x[(((n * IN_C + ic) * HW) + y) * HW + pix] * gain[n * IN_C + ic];
        lds[pix][ic] = f2bf(v);
    }
    __syncthreads();
    unsigned int* dst = (unsigned int*)(xg + (((size_t)(n * PHW) + y + 1) * PHW + 1) * 128);
    for (int i = tid; i < 8192; i += 256) {
        int pix = i >> 6, d = i & 63;
        int j = d >> 2, ww = d & 3;
        int js = j ^ ((pix + 1) & 7);          // swizzle key = padded X & 7
        dst[pix * 64 + js * 4 + ww] = *reinterpret_cast<const unsigned int*>(&lds[pix][d * 2]);
    }
}

// ---------------- main conv: M=256 x N=256px x K=1152, split into 1024 blocks of 128px.
// Wave tile 64M x 64px -> acc[4][4]=64 AGPR; total regs <=128 -> 4 waves/SIMD,
// 2 blocks/CU (LDS 2 x 46KB). A reg-dbuf one half-step ahead; B JIT from resident halo.
// No K-loop barriers; compiler-counted waits; latency hidden by 4-wave TLP.
#define MM(ACC, AF, BF) ACC = __builtin_amdgcn_mfma_f32_16x16x32_bf16(AF, BF, ACC, 0, 0, 0)

__global__ __launch_bounds__(512, 4) void conv_mfma11(
    const unsigned short* __restrict__ xg,
    const unsigned short* __restrict__ wb2,
    const float* __restrict__ bias,
    float* __restrict__ out) {
    __shared__ __align__(16) char haloB[46080];   // 10 rows x 18 px x 256B

    const int bid = blockIdx.x;                 // 1024 blocks; bijective XCD swizzle (1024%8==0)
    const int wg  = ((bid & 7) << 7) + (bid >> 3);
    const int n     = wg >> 7;
    const int patch = wg & 127;
    const int Y0 = (patch >> 3) * 8;            // halo start row (padded coords)
    const int X0 = (patch & 7) * 16;            // mult of 8 -> swizzle key block-independent
    const int tid  = threadIdx.x;
    const int lane = tid & 63;
    const int wid  = tid >> 6;
    const int q  = wid & 3;                     // M-quarter; SIMD-cohabitants (wid, wid+4) share q
    const int wN = wid >> 2;                    // 0..1 -> 4 pixel-rows each
    const int l16 = lane & 15;
    const int lhi = lane >> 4;
    const int pbase = wN * 4;

    const char* xgb = (const char*)xg + (size_t)n * PHW * PHW * 256;

    // ---- stage halo once: 10 rows x 18 px x 256B = 2880 chunks of 16B, linear LDS
    #pragma unroll 1
    for (int i = 0; i < 6; ++i) {
        int cc = i * 512 + tid;
        if (cc < 2880) {                        // cutoff at wave boundary (320 = 5 waves)
            int r = cc / 288;
            int t2 = cc - r * 288;
            gload16(xgb + ((size_t)(Y0 + r) * PHW + X0) * 256 + t2 * 16,
                    haloB + (i * 512 + wid * 64) * 16);
        }
    }

    // per-lane A base for M-quarter q (wMold = q&1, hh = q>>1):
    //   frag f of (t,kc) at abase + t*32768 + kc*8192 + f*1024
    const char* abase = (const char*)wb2 + ((q >> 1) << 14) + ((q & 1) << 12) + (lane << 4);

    f32x4 acc[4][4];
    #pragma unroll
    for (int f = 0; f < 4; ++f)
        #pragma unroll
        for (int b = 0; b < 4; ++b) acc[f][b] = (f32x4)0.f;

    __syncthreads();   // halo resident for all waves (drains vmcnt before barrier)

    short8 Aa[4], Ab[4], Bf[4];

    auto loadA = [&](short8 (&A)[4], int t, int kc) {
        const char* ak = abase + t * 32768 + kc * 8192;
        #pragma unroll
        for (int f = 0; f < 4; ++f)
            A[f] = *reinterpret_cast<const short8*>(ak + (f << 10));
    };
    // rowb = (pbase+ky)*18 + C ; off folds h,kc,lhi and the X-swizzle
    auto loadB = [&](short8 (&B)[4], int rowb, int off) {
        #pragma unroll
        for (int b = 0; b < 4; ++b)
            B[b] = *reinterpret_cast<const short8*>(haloB + ((rowb + b * 18) << 8) + off);
    };
    auto cluster = [&](short8 (&A)[4], short8 (&B)[4]) {
        __builtin_amdgcn_s_setprio(1);
        #pragma unroll
        for (int f = 0; f < 4; ++f)
            #pragma unroll
            for (int b = 0; b < 4; ++b) MM(acc[f][b], A[f], B[b]);
        __builtin_amdgcn_s_setprio(0);
    };

    // prime A(t=0, kc=0)
    loadA(Aa, 0, 0);

    #pragma unroll 1
    for (int t = 0; t < 18; ++t) {
        const int tap = t >> 1;
        const int h   = t & 1;
        const int ky  = tap / 3;
        const int kx  = tap - ky * 3;
        const int C   = l16 + kx;
        const int bswz = (C & 7) << 4;
        const int rowb = (pbase + ky) * 18 + C;

        // ===== half kc=0: prefetch A(t,1); B JIT; cluster on (t, kc=0)
        loadA(Ab, t, 1);
        loadB(Bf, rowb, ((h << 7) + (lhi << 4)) ^ bswz);
        __builtin_amdgcn_sched_barrier(0);
        cluster(Aa, Bf);

        // ===== half kc=1: prefetch A(t+1,0); B JIT; cluster on (t, kc=1)
        if (t + 1 < 18) loadA(Aa, t + 1, 0);
        loadB(Bf, rowb, ((h << 7) + 64 + (lhi << 4)) ^ bswz);
        __builtin_amdgcn_sched_barrier(0);
        cluster(Ab, Bf);
    }

    // ---- epilogue: M = (q&1)*128 + (q>>1)*64 + f*16 + lhi*4 + r ; oc = M>>2, phase = r
    #pragma unroll
    for (int f = 0; f < 4; ++f) {
        const int oc = (q & 1) * 32 + (q >> 1) * 16 + f * 4 + lhi;
        const float bi = bias[oc];
        #pragma unroll
        for (int b = 0; b < 4; ++b) {
            const int ypix = Y0 + pbase + b;
            const int xpix = X0 + l16;
            float* o0 = out + (((size_t)(n * OUT_C + oc) * OHW) + 2 * ypix) * OHW + 2 * xpix;
            float2 v0 = make_float2(postact(acc[f][b][0] + bi), postact(acc[f][b][1] + bi));
            float2 v1 = make_float2(postact(acc[f][b][2] + bi), postact(acc[f][b][3] + bi));
            *reinterpret_cast<float2*>(o0) = v0;
            *reinterpret_cast<float2*>(o0 + OHW) = v1;
        }
    }
}

// ================= fallback f32 path (round-1, verified) =================
__global__ void gain_kernel(const float* __restrict__ c,
                            const float* __restrict__ w_affine,
                            const float* __restrict__ b_affine,
                            float* __restrict__ gain) {
    int wave = (blockIdx.x * blockDim.x + threadIdx.x) >> 6;
    int lane = threadIdx.x & 63;
    if (wave >= NB * IN_C) return;
    int n  = wave >> 7;
    int ic = wave & 127;
    const float* cp = c + n * CDIM;
    const float* wp = w_affine + ic * CDIM;
    float s = 0.f;
    #pragma unroll
    for (int k = 0; k < CDIM / 64; ++k) s += cp[lane + 64 * k] * wp[lane + 64 * k];
    #pragma unroll
    for (int off = 32; off > 0; off >>= 1) s += __shfl_down(s, off);
    if (lane == 0) {
        float y = s * 0.04419417382415922f + b_affine[ic];
        gain[n * IN_C + ic] = 1.0f + tanhf(y);
    }
}

__global__ void wprep_kernel(const float* __restrict__ w, float* __restrict__ wp) {
    int idx = blockIdx.x * blockDim.x + threadIdx.x;
    if (idx >= IN_C * 9 * 4 * OUT_C) return;
    int oc = idx & 63;
    int t  = idx >> 6;
    int ph = t & 3;  t >>= 2;
    int kx = t % 3;  t /= 3;
    int ky = t % 3;  t /= 3;
    int ic = t;
    int py = ph >> 1, px = ph & 1;
    int sy = 2 * ky + (py == 0 ? 1 : 0);
    int sx = 2 * kx + (px == 0 ? 1 : 0);
    const float k1[4] = {0.25f, 0.75f, 0.75f, 0.25f};
    float sum = 0.f;
    #pragma unroll
    for (int by = 0; by < 3; ++by) {
        int ay = sy - by;
        if (ay < 0 || ay > 3) continue;
        #pragma unroll
        for (int bx = 0; bx < 3; ++bx) {
            int ax = sx - bx;
            if (ax < 0 || ax > 3) continue;
            sum += w[((oc * IN_C + ic) * 3 + (2 - by)) * 3 + (2 - bx)] * k1[ay] * k1[ax];
        }
    }
    wp[idx] = sum * 0.029462782549439483f;
}

__global__ __launch_bounds__(256) void conv_main(
    const float* __restrict__ x, const float* __restrict__ gain,
    const float* __restrict__ wp, const float* __restrict__ bias,
    float* __restrict__ out) {
    const int n    = blockIdx.z >> 3;
    const int occ  = (blockIdx.z & 7) * 8;
    const int tx0  = blockIdx.x * 16;
    const int ty0  = blockIdx.y * 16;
    const int tid  = threadIdx.x;
    const int lx   = tid & 15;
    const int ly   = tid >> 4;
    __shared__ float xsf[8][18][18];
    float acc[4][8];
    #pragma unroll
    for (int p = 0; p < 4; ++p)
        #pragma unroll
        for (int o = 0; o < 8; ++o) acc[p][o] = 0.f;
    for (int ic0 = 0; ic0 < IN_C; ic0 += 8) {
        __syncthreads();
        for (int i = tid; i < 8 * 324; i += 256) {
            int icb = i / 324;
            int rem = i - icb * 324;
            int yy  = rem / 18;
            int xx  = rem - yy * 18;
            int gy  = ty0 + yy - 1;
            int gx  = tx0 + xx - 1;
            int ic  = ic0 + icb;
            float v = 0.f;
            if (gy >= 0 && gy < HW && gx >= 0 && gx < HW)
                v = x[((n * IN_C + ic) * HW + gy) * HW + gx] * gain[n * IN_C + ic];
            xsf[icb][yy][xx] = v;
        }
        __syncthreads();
        for (int icb = 0; icb < 8; ++icb) {
            const int ic = ic0 + icb;
            const float* wpp = wp + ic * (9 * 4 * OUT_C) + occ;
            #pragma unroll
            for (int ky = 0; ky < 3; ++ky)
                #pragma unroll
                for (int kx = 0; kx < 3; ++kx) {
                    float tv = xsf[icb][ly + ky][lx + kx];
                    const float* w9 = wpp + (ky * 3 + kx) * (4 * OUT_C);
                    #pragma unroll
                    for (int p = 0; p < 4; ++p)
                        #pragma unroll
                        for (int o = 0; o < 8; ++o)
                            acc[p][o] = fmaf(tv, w9[p * OUT_C + o], acc[p][o]);
                }
        }
    }
    const int ybase = 2 * (ty0 + ly);
    const int xbase = 2 * (tx0 + lx);
    #pragma unroll
    for (int o = 0; o < 8; ++o) {
        float b = bias[occ + o];
        #pragma unroll
        for (int py = 0; py < 2; ++py) {
            float2 v;
            v.x = postact(acc[py * 2 + 0][o] + b);
            v.y = postact(acc[py * 2 + 1][o] + b);
            *reinterpret_cast<float2*>(
                &out[((size_t)(n * OUT_C + occ + o) * OHW + (ybase + py)) * OHW + xbase]) = v;
        }
    }
}

extern "C" void kernel_launch(void* const* d_in, const int* in_sizes, int n_in,
                              void* d_out, int out_size, void* d_ws, size_t ws_size,
                              hipStream_t stream) {
    const float* x        = (const float*)d_in[0];
    const float* c        = (const float*)d_in[1];
    const float* weight   = (const float*)d_in[2];
    const float* bias     = (const float*)d_in[3];
    const float* w_affine = (const float*)d_in[4];
    const float* b_affine = (const float*)d_in[5];
    float* out = (float*)d_out;

    float* gain = (float*)d_ws;   // 4 KB @ 0

    const size_t NEED = 1048576 + (size_t)NB * PHW * PHW * IN_C * 2;  // ~35.7 MB
    if (ws_size >= NEED) {
        unsigned short* wb2 = (unsigned short*)((char*)d_ws + 8192);      // 589824 B
        unsigned short* xg  = (unsigned short*)((char*)d_ws + 1048576);   // 34.6 MB padded+swizzled NHWC
        prep_kernel<<<dim3(1666), dim3(256), 0, stream>>>(weight, wb2, xg, c, w_affine, b_affine, gain);
        xprep_kernel<<<dim3(NB * HW), dim3(256), 0, stream>>>(x, gain, xg);
        conv_mfma11<<<dim3(1024), dim3(512), 0, stream>>>(xg, wb2, bias, out);
    } else {
        float* wp = (float*)((char*)d_ws + 8192);
        gain_kernel<<<dim3((NB * IN_C * 64) / 256), dim3(256), 0, stream>>>(c, w_affine, b_affine, gain);
        wprep_kernel<<<dim3((IN_C * 9 * 4 * OUT_C + 255) / 256), dim3(256), 0, stream>>>(weight, wp);
        conv_main<<<dim3(HW / 16, HW / 16, NB * 8), dim3(256), 0, stream>>>(x, gain, wp, bias, out);
    }
}